// Round 3
// baseline (728.812 us; speedup 1.0000x reference)
//
#include <hip/hip_runtime.h>
#include <stdint.h>

// CAFormer fused block, MI355X gfx950.
// I/O dtypes: ALL inputs fp32, d_out fp32 (per reference). Internal
// intermediates (qkv, oh, ov) are bf16 — tolerance is bf16-mode (2% of maxref).
// ws layout (~160.0 MB, known-safe: R2's 160 MB footprint ran without fault):
//   qkv bf16 [4][192][65536] @ 0          (100663296 B)
//   oh  bf16 [4][64][65536]  @ 100663296  (33554432 B)
//   ov  bf16                 @ 134217728  (33554432 B)
//   f32 scratch @ 167772160: gxsum[256] cwaw[8] rnorm[512]  (3104 B)
// conv result (pre-scaled by cw) goes directly into d_out (fp32); k_final
// mixes + projects in place (thread-local pixel columns -> RAW-safe).

typedef unsigned short u16;
typedef __attribute__((ext_vector_type(8))) short bf16x8;
typedef __attribute__((ext_vector_type(4))) float f32x4;

#define DEV static __device__ __forceinline__

DEV u16 f2bf(float f) {
  unsigned u = __float_as_uint(f);
  return (u16)((u + 0x7fffu + ((u >> 16) & 1u)) >> 16);
}
DEV float bf2f(u16 h) { return __uint_as_float(((unsigned)h) << 16); }

// ---------------- gating: per-(b,c) spatial sum of x ----------------
__global__ void k_gx(const float* __restrict__ x, float* __restrict__ gxsum) {
  int bc = blockIdx.x, t = threadIdx.x;
  const float4* p = (const float4*)(x + ((size_t)bc << 16));
  float s = 0.f;
  for (int i = 0; i < 64; ++i) { float4 v = p[t + 256 * i]; s += v.x + v.y + v.z + v.w; }
  for (int off = 32; off; off >>= 1) s += __shfl_down(s, off);
  __shared__ float lds[4];
  if ((t & 63) == 0) lds[t >> 6] = s;
  __syncthreads();
  if (t == 0) gxsum[bc] = lds[0] + lds[1] + lds[2] + lds[3];
}

// ---------------- gating MLP -> cw/aw per batch ----------------
__global__ void k_gate(const float* __restrict__ gxsum, const float* __restrict__ g1w,
                       const float* __restrict__ g1b, const float* __restrict__ g2w,
                       const float* __restrict__ g2b, float* __restrict__ cwaw) {
  __shared__ float h1[4][16];
  int t = threadIdx.x;
  int b = t >> 4, j = t & 15;
  float a = g1b[j];
  for (int c = 0; c < 64; ++c) a += g1w[j * 64 + c] * gxsum[b * 64 + c] * (1.f / 65536.f);
  h1[b][j] = fmaxf(a, 0.f);
  __syncthreads();
  if (t < 4) {
    float l0 = g2b[0], l1 = g2b[1];
    for (int k = 0; k < 16; ++k) { l0 += g2w[k] * h1[t][k]; l1 += g2w[16 + k] * h1[t][k]; }
    float m = fmaxf(l0, l1);
    float e0 = __expf(l0 - m), e1 = __expf(l1 - m);
    float inv = 1.f / (e0 + e1);
    cwaw[t * 2 + 0] = e0 * inv;  // conv weight
    cwaw[t * 2 + 1] = e1 * inv;  // attn weight
  }
}

// ---------------- qkv projection: 192x64 per pixel, fp32 -> bf16 ----------------
__global__ __launch_bounds__(256) void k_qkv(const float* __restrict__ x,
                                             const float* __restrict__ wqkv,
                                             u16* __restrict__ qkv) {
  int b = blockIdx.x >> 8;
  int p = ((blockIdx.x & 255) << 8) | threadIdx.x;
  float xr[64];
#pragma unroll
  for (int c = 0; c < 64; ++c) xr[c] = x[(((size_t)(b * 64 + c)) << 16) + p];
  for (int o = 0; o < 192; ++o) {
    const float* wr = wqkv + o * 64;  // wave-uniform -> SGPR loads
    float a0 = 0.f, a1 = 0.f;
#pragma unroll
    for (int c = 0; c < 64; c += 2) { a0 = fmaf(wr[c], xr[c], a0); a1 = fmaf(wr[c + 1], xr[c + 1], a1); }
    qkv[(((size_t)(b * 192 + o)) << 16) + p] = f2bf(a0 + a1);
  }
}

// ---------------- 1/||plane|| for q,k channels (from bf16 qkv) ----------------
__global__ void k_rnorm(const u16* __restrict__ qkv, float* __restrict__ rnorm) {
  int b = blockIdx.x >> 7, ch = blockIdx.x & 127;
  const uint2* p2 = (const uint2*)(qkv + ((size_t)(b * 192 + ch) << 16));
  int t = threadIdx.x;
  float s = 0.f;
  for (int i = 0; i < 64; ++i) {
    uint2 v = p2[t + 256 * i];
    float a = bf2f(v.x & 0xffff), bq = bf2f(v.x >> 16);
    float c = bf2f(v.y & 0xffff), d = bf2f(v.y >> 16);
    s += a * a + bq * bq + c * c + d * d;
  }
  for (int off = 32; off; off >>= 1) s += __shfl_down(s, off);
  __shared__ float lds[4];
  if ((t & 63) == 0) lds[t >> 6] = s;
  __syncthreads();
  if (t == 0) {
    float tot = lds[0] + lds[1] + lds[2] + lds[3];
    rnorm[blockIdx.x] = 1.f / fmaxf(sqrtf(tot), 1e-12f);
  }
}

// ---------------- depthwise 3x3+5x5 conv, writes cw*conv to d_out (fp32) ----------------
__global__ void k_conv(const float* __restrict__ x, const float* __restrict__ w3,
                       const float* __restrict__ b3, const float* __restrict__ w5,
                       const float* __restrict__ b5, const float* __restrict__ cwaw,
                       float* __restrict__ outmix) {
  int rt = blockIdx.x & 31, bc = blockIdx.x >> 5, c = bc & 63, b = bc >> 6;
  int r0 = rt * 8;
  const float* xp = x + ((size_t)bc << 16);
  __shared__ float xs[12][256];
  int y = threadIdx.x;
  for (int rr = 0; rr < 12; ++rr) {
    int gr = r0 - 2 + rr;
    xs[rr][y] = (gr >= 0 && gr < 256) ? xp[(size_t)gr * 256 + y] : 0.f;
  }
  __syncthreads();
  float W3[9], W5[25];
#pragma unroll
  for (int i = 0; i < 9; ++i) W3[i] = w3[c * 9 + i];
#pragma unroll
  for (int i = 0; i < 25; ++i) W5[i] = w5[c * 25 + i];
  float bias = b3[c] + b5[c];
  float cw = cwaw[b * 2];
  float* op = outmix + ((size_t)bc << 16);
  for (int k = 0; k < 8; ++k) {
    float a = bias;
#pragma unroll
    for (int di = 0; di < 3; ++di)
#pragma unroll
      for (int dj = 0; dj < 3; ++dj) {
        int yy = y + dj - 1;
        float xv = (yy >= 0 && yy < 256) ? xs[k + 1 + di][yy] : 0.f;
        a += W3[di * 3 + dj] * xv;
      }
#pragma unroll
    for (int di = 0; di < 5; ++di)
#pragma unroll
      for (int dj = 0; dj < 5; ++dj) {
        int yy = y + dj - 2;
        float xv = (yy >= 0 && yy < 256) ? xs[k + di][yy] : 0.f;
        a += W5[di * 5 + dj] * xv;
      }
    op[(size_t)(r0 + k) * 256 + y] = cw * a;
  }
}

// ---------------- axial attention, MFMA bf16, operands direct from global ----------------
// block = (b, c, dir, rowtile of 64). dir0: rows=h (attend along w); dir1: rows=w.
__global__ __launch_bounds__(256) void k_attn(
    const u16* __restrict__ qkv, const float* __restrict__ rnorm,
    const float* __restrict__ scale, u16* __restrict__ oh, u16* __restrict__ ov) {
  __shared__ __align__(16) unsigned char smem[34816];
  u16* Pls = (u16*)smem;                // [64][264] bf16
  float* red = (float*)(smem + 33792);  // [4][64]
  float* Osf = (float*)smem;            // [32][260] (dir1 store; Pls dead, barrier-protected)

  int t = threadIdx.x;
  int w = t >> 6, l = t & 63, q = l >> 4, cl = l & 15;
  int idx = blockIdx.x;
  int rt = idx & 3, dir = (idx >> 2) & 1, c = (idx >> 3) & 63, b = idx >> 9;
  int r0 = rt << 6;

  const size_t P = 65536;
  const u16* Qp = qkv + (size_t)(b * 192 + c) * P;
  const u16* Kp = qkv + (size_t)(b * 192 + 64 + c) * P;
  const u16* Vp = qkv + (size_t)(b * 192 + 128 + c) * P;

  float sc = rnorm[b * 128 + c] * rnorm[b * 128 + 64 + c] * scale[c >> 3];

  f32x4 Sa[4][4];
  f32x4 zero = {0.f, 0.f, 0.f, 0.f};
#pragma unroll
  for (int i = 0; i < 4; ++i)
#pragma unroll
    for (int j = 0; j < 4; ++j) Sa[i][j] = zero;

  // ---- S phase: 8 k-windows of 32 ----
  for (int yw = 0; yw < 8; ++yw) {
    int y0 = yw << 5;
    bf16x8 af[4], bfr[4];
    if (dir == 0) {
#pragma unroll
      for (int i = 0; i < 4; ++i)
        af[i] = *(const bf16x8*)&Qp[(size_t)(r0 + i * 16 + cl) * 256 + y0 + q * 8];
#pragma unroll
      for (int j = 0; j < 4; ++j)
        bfr[j] = *(const bf16x8*)&Kp[(size_t)(w * 64 + j * 16 + cl) * 256 + y0 + q * 8];
    } else {
#pragma unroll
      for (int i = 0; i < 4; ++i) {
        bf16x8 tmp;
#pragma unroll
        for (int jj = 0; jj < 8; ++jj)
          tmp[jj] = (short)Qp[(y0 + q * 8 + jj) * 256 + r0 + i * 16 + cl];
        af[i] = tmp;
      }
#pragma unroll
      for (int j = 0; j < 4; ++j) {
        bf16x8 tmp;
#pragma unroll
        for (int jj = 0; jj < 8; ++jj)
          tmp[jj] = (short)Kp[(y0 + q * 8 + jj) * 256 + w * 64 + j * 16 + cl];
        bfr[j] = tmp;
      }
    }
#pragma unroll
    for (int i = 0; i < 4; ++i)
#pragma unroll
      for (int j = 0; j < 4; ++j)
        Sa[i][j] = __builtin_amdgcn_mfma_f32_16x16x32_bf16(af[i], bfr[j], Sa[i][j], 0, 0, 0);
  }

  // ---- softmax over cols (rows = i*16+q*4+r, cols = w*64+j*16+cl) ----
#pragma unroll
  for (int i = 0; i < 4; ++i)
#pragma unroll
    for (int j = 0; j < 4; ++j) Sa[i][j] *= sc;

  float mx[4][4], sm[4][4];
#pragma unroll
  for (int i = 0; i < 4; ++i)
#pragma unroll
    for (int r = 0; r < 4; ++r) {
      float m = fmaxf(fmaxf(Sa[i][0][r], Sa[i][1][r]), fmaxf(Sa[i][2][r], Sa[i][3][r]));
#pragma unroll
      for (int off = 1; off < 16; off <<= 1) m = fmaxf(m, __shfl_xor(m, off));
      mx[i][r] = m;
    }
  if (cl == 0) {
#pragma unroll
    for (int i = 0; i < 4; ++i)
#pragma unroll
      for (int r = 0; r < 4; ++r) red[w * 64 + i * 16 + q * 4 + r] = mx[i][r];
  }
  __syncthreads();
#pragma unroll
  for (int i = 0; i < 4; ++i)
#pragma unroll
    for (int r = 0; r < 4; ++r) {
      int rho = i * 16 + q * 4 + r;
      mx[i][r] = fmaxf(fmaxf(red[rho], red[64 + rho]), fmaxf(red[128 + rho], red[192 + rho]));
    }
  __syncthreads();
#pragma unroll
  for (int i = 0; i < 4; ++i)
#pragma unroll
    for (int r = 0; r < 4; ++r) {
      float s0 = 0.f;
#pragma unroll
      for (int j = 0; j < 4; ++j) {
        float e = __expf(Sa[i][j][r] - mx[i][r]);
        Sa[i][j][r] = e;
        s0 += e;
      }
#pragma unroll
      for (int off = 1; off < 16; off <<= 1) s0 += __shfl_xor(s0, off);
      sm[i][r] = s0;
    }
  if (cl == 0) {
#pragma unroll
    for (int i = 0; i < 4; ++i)
#pragma unroll
      for (int r = 0; r < 4; ++r) red[w * 64 + i * 16 + q * 4 + r] = sm[i][r];
  }
  __syncthreads();
#pragma unroll
  for (int i = 0; i < 4; ++i)
#pragma unroll
    for (int r = 0; r < 4; ++r) {
      int rho = i * 16 + q * 4 + r;
      sm[i][r] = 1.f / (red[rho] + red[64 + rho] + red[128 + rho] + red[192 + rho]);
    }
  // P -> LDS row-major [row][z]
#pragma unroll
  for (int i = 0; i < 4; ++i)
#pragma unroll
    for (int r = 0; r < 4; ++r) {
      int rho = i * 16 + q * 4 + r;
#pragma unroll
      for (int j = 0; j < 4; ++j)
        Pls[rho * 264 + w * 64 + j * 16 + cl] = f2bf(Sa[i][j][r] * sm[i][r]);
    }
  __syncthreads();

  // ---- O = P V over 8 z-windows ----
  f32x4 Oa[4][4];
#pragma unroll
  for (int i = 0; i < 4; ++i)
#pragma unroll
    for (int j = 0; j < 4; ++j) Oa[i][j] = zero;
  for (int zw = 0; zw < 8; ++zw) {
    int z0 = zw << 5;
    bf16x8 af[4], bfr[4];
#pragma unroll
    for (int i = 0; i < 4; ++i) af[i] = *(const bf16x8*)&Pls[(i * 16 + cl) * 264 + z0 + q * 8];
    if (dir == 0) {
#pragma unroll
      for (int j = 0; j < 4; ++j) {
        bf16x8 tmp;
#pragma unroll
        for (int jj = 0; jj < 8; ++jj)
          tmp[jj] = (short)Vp[(z0 + q * 8 + jj) * 256 + w * 64 + j * 16 + cl];
        bfr[j] = tmp;
      }
    } else {
#pragma unroll
      for (int j = 0; j < 4; ++j)
        bfr[j] = *(const bf16x8*)&Vp[(size_t)(w * 64 + j * 16 + cl) * 256 + z0 + q * 8];
    }
#pragma unroll
    for (int i = 0; i < 4; ++i)
#pragma unroll
      for (int j = 0; j < 4; ++j)
        Oa[i][j] = __builtin_amdgcn_mfma_f32_16x16x32_bf16(af[i], bfr[j], Oa[i][j], 0, 0, 0);
  }

  // ---- store ----
  if (dir == 0) {
    u16* op = oh + (size_t)(b * 64 + c) * P;
#pragma unroll
    for (int i = 0; i < 4; ++i)
#pragma unroll
      for (int j = 0; j < 4; ++j)
#pragma unroll
        for (int r = 0; r < 4; ++r)
          op[(size_t)(r0 + i * 16 + q * 4 + r) * 256 + w * 64 + j * 16 + cl] = f2bf(Oa[i][j][r]);
  } else {
    u16* op = ov + (size_t)(b * 64 + c) * P;
    __syncthreads();  // Pls (aliasing Osf) may still be read by lagging waves
    for (int h = 0; h < 2; ++h) {
#pragma unroll
      for (int ii = 0; ii < 2; ++ii) {
        int i = h * 2 + ii;
#pragma unroll
        for (int j = 0; j < 4; ++j)
#pragma unroll
          for (int r = 0; r < 4; ++r)
            Osf[(ii * 16 + q * 4 + r) * 260 + w * 64 + j * 16 + cl] = Oa[i][j][r];
      }
      __syncthreads();
      int rr = t & 31, xb = t >> 5;
      for (int xx = 0; xx < 32; ++xx) {
        int xcol = xx * 8 + xb;
        op[(size_t)xcol * 256 + r0 + h * 32 + rr] = f2bf(Osf[rr * 260 + xcol]);
      }
      __syncthreads();
    }
  }
}

// ---------------- mix + 64x64 projection, in place on d_out (fp32) ----------------
__global__ __launch_bounds__(256) void k_final(
    float* __restrict__ dout, const u16* __restrict__ oh, const u16* __restrict__ ov,
    const float* __restrict__ wp, const float* __restrict__ bp,
    const float* __restrict__ cwaw) {
  int b = blockIdx.x >> 8;
  int p = ((blockIdx.x & 255) << 8) | threadIdx.x;
  float aw = cwaw[b * 2 + 1];
  float m[64];
#pragma unroll
  for (int c = 0; c < 64; ++c) {
    size_t off = (((size_t)(b * 64 + c)) << 16) + p;
    m[c] = dout[off] + aw * (bf2f(oh[off]) + bf2f(ov[off]));
  }
  for (int o = 0; o < 64; ++o) {
    const float* wr = wp + o * 64;  // uniform -> SGPR
    float a0 = bp[o], a1 = 0.f;
#pragma unroll
    for (int c = 0; c < 64; c += 2) { a0 = fmaf(wr[c], m[c], a0); a1 = fmaf(wr[c + 1], m[c + 1], a1); }
    dout[(((size_t)(b * 64 + o)) << 16) + p] = a0 + a1;
  }
}

extern "C" void kernel_launch(void* const* d_in, const int* in_sizes, int n_in,
                              void* d_out, int out_size, void* d_ws, size_t ws_size,
                              hipStream_t stream) {
  const float* x = (const float*)d_in[0];
  const float* w3 = (const float*)d_in[1];
  const float* b3 = (const float*)d_in[2];
  const float* w5 = (const float*)d_in[3];
  const float* b5 = (const float*)d_in[4];
  const float* wqkv = (const float*)d_in[5];
  const float* scale = (const float*)d_in[6];
  const float* g1w = (const float*)d_in[7];
  const float* g1b = (const float*)d_in[8];
  const float* g2w = (const float*)d_in[9];
  const float* g2b = (const float*)d_in[10];
  const float* wp = (const float*)d_in[11];
  const float* bp = (const float*)d_in[12];
  float* out = (float*)d_out;

  char* ws = (char*)d_ws;
  u16* qkv = (u16*)(ws);
  u16* ohb = (u16*)(ws + 100663296ull);
  u16* ovb = (u16*)(ws + 134217728ull);
  float* fs = (float*)(ws + 167772160ull);
  float* gxsum = fs;        // 256
  float* cwaw = fs + 256;   // 8
  float* rnorm = fs + 264;  // 512

  k_gx<<<256, 256, 0, stream>>>(x, gxsum);
  k_gate<<<1, 64, 0, stream>>>(gxsum, g1w, g1b, g2w, g2b, cwaw);
  k_qkv<<<1024, 256, 0, stream>>>(x, wqkv, qkv);
  k_rnorm<<<512, 256, 0, stream>>>(qkv, rnorm);
  k_conv<<<8192, 256, 0, stream>>>(x, w3, b3, w5, b5, cwaw, out);
  k_attn<<<2048, 256, 0, stream>>>(qkv, rnorm, scale, ohb, ovb);
  k_final<<<1024, 256, 0, stream>>>(out, ohb, ovb, wp, bp, cwaw);
}

// Round 4
// 379.811 us; speedup vs baseline: 1.9189x; 1.9189x over previous
//
#include <hip/hip_runtime.h>
#include <stdint.h>

// CAFormer fused block, MI355X gfx950.
// I/O: all inputs fp32, d_out fp32. Internal intermediates bf16.
// R4: k_qkv and k_final are now bf16 MFMA GEMMs (R3 showed k_qkv=327us,
// VALUBusy 29%, latency-bound fp32 VALU GEMM).
// ws layout (~160.0 MB):
//   qkv bf16 [4][192][65536] @ 0          (100663296 B)
//   oh  bf16 [4][64][65536]  @ 100663296  (33554432 B)
//   ov  bf16                 @ 134217728  (33554432 B)
//   f32 scratch @ 167772160: gxsum[256] cwaw[8] rnorm[512]

typedef unsigned short u16;
typedef __attribute__((ext_vector_type(8))) short bf16x8;
typedef __attribute__((ext_vector_type(4))) float f32x4;

#define DEV static __device__ __forceinline__

DEV u16 f2bf(float f) {
  unsigned u = __float_as_uint(f);
  return (u16)((u + 0x7fffu + ((u >> 16) & 1u)) >> 16);
}
DEV float bf2f(u16 h) { return __uint_as_float(((unsigned)h) << 16); }

// ---------------- gating: per-(b,c) spatial sum of x ----------------
__global__ void k_gx(const float* __restrict__ x, float* __restrict__ gxsum) {
  int bc = blockIdx.x, t = threadIdx.x;
  const float4* p = (const float4*)(x + ((size_t)bc << 16));
  float s = 0.f;
  for (int i = 0; i < 64; ++i) { float4 v = p[t + 256 * i]; s += v.x + v.y + v.z + v.w; }
  for (int off = 32; off; off >>= 1) s += __shfl_down(s, off);
  __shared__ float lds[4];
  if ((t & 63) == 0) lds[t >> 6] = s;
  __syncthreads();
  if (t == 0) gxsum[bc] = lds[0] + lds[1] + lds[2] + lds[3];
}

// ---------------- gating MLP -> cw/aw per batch ----------------
__global__ void k_gate(const float* __restrict__ gxsum, const float* __restrict__ g1w,
                       const float* __restrict__ g1b, const float* __restrict__ g2w,
                       const float* __restrict__ g2b, float* __restrict__ cwaw) {
  __shared__ float h1[4][16];
  int t = threadIdx.x;
  int b = t >> 4, j = t & 15;
  float a = g1b[j];
  for (int c = 0; c < 64; ++c) a += g1w[j * 64 + c] * gxsum[b * 64 + c] * (1.f / 65536.f);
  h1[b][j] = fmaxf(a, 0.f);
  __syncthreads();
  if (t < 4) {
    float l0 = g2b[0], l1 = g2b[1];
    for (int k = 0; k < 16; ++k) { l0 += g2w[k] * h1[t][k]; l1 += g2w[16 + k] * h1[t][k]; }
    float m = fmaxf(l0, l1);
    float e0 = __expf(l0 - m), e1 = __expf(l1 - m);
    float inv = 1.f / (e0 + e1);
    cwaw[t * 2 + 0] = e0 * inv;  // conv weight
    cwaw[t * 2 + 1] = e1 * inv;  // attn weight
  }
}

// ---------------- qkv projection as MFMA GEMM: [192x64] x [64x128px] ----------------
// block: all 192 out-rows x 128 pixels. wave w: rows w*48..w*48+47 (3 groups of 16).
__global__ __launch_bounds__(256) void k_qkv(const float* __restrict__ x,
                                             const float* __restrict__ wqkv,
                                             u16* __restrict__ qkv) {
  __shared__ u16 Ws[192 * 72];  // A: [row][ch], stride 72 shorts
  __shared__ u16 Xs[128 * 72];  // B^T: [px][ch]
  int t = threadIdx.x;
  int b = blockIdx.x >> 9;
  int p0 = (blockIdx.x & 511) << 7;

  // stage wqkv (192x64 fp32 -> bf16)
  {
    int row = t >> 2, c0 = (t & 3) << 4;
#pragma unroll
    for (int i = 0; i < 3; ++i) {
      int r = i * 64 + row;
      const float* src = wqkv + r * 64 + c0;
      unsigned pk[8];
#pragma unroll
      for (int j = 0; j < 8; ++j)
        pk[j] = (unsigned)f2bf(src[2 * j]) | ((unsigned)f2bf(src[2 * j + 1]) << 16);
      uint4* dst = (uint4*)&Ws[r * 72 + c0];
      dst[0] = make_uint4(pk[0], pk[1], pk[2], pk[3]);
      dst[1] = make_uint4(pk[4], pk[5], pk[6], pk[7]);
    }
  }
  // stage x tile: 64ch x 128px, transposed -> Xs[px][ch]
  {
    int p = t & 127, ch = t >> 7;  // waves 0/1: even ch, waves 2/3: odd ch
    const float* xb = x + ((size_t)(b * 64) << 16) + p0 + p;
#pragma unroll
    for (int i = 0; i < 32; ++i) {
      int c = 2 * i + ch;
      Xs[p * 72 + c] = f2bf(xb[(size_t)c << 16]);
    }
  }
  __syncthreads();

  int w = t >> 6, l = t & 63, q = l >> 4, cl = l & 15;
  bf16x8 af[3][2];
#pragma unroll
  for (int g = 0; g < 3; ++g)
#pragma unroll
    for (int k = 0; k < 2; ++k)
      af[g][k] = *(const bf16x8*)&Ws[(w * 48 + g * 16 + cl) * 72 + k * 32 + q * 8];

  f32x4 acc[3][8];
  f32x4 zero = {0.f, 0.f, 0.f, 0.f};
#pragma unroll
  for (int g = 0; g < 3; ++g)
#pragma unroll
    for (int j = 0; j < 8; ++j) acc[g][j] = zero;

  for (int j = 0; j < 8; ++j) {
    bf16x8 b0 = *(const bf16x8*)&Xs[(j * 16 + cl) * 72 + q * 8];
    bf16x8 b1 = *(const bf16x8*)&Xs[(j * 16 + cl) * 72 + 32 + q * 8];
#pragma unroll
    for (int g = 0; g < 3; ++g) {
      acc[g][j] = __builtin_amdgcn_mfma_f32_16x16x32_bf16(af[g][0], b0, acc[g][j], 0, 0, 0);
      acc[g][j] = __builtin_amdgcn_mfma_f32_16x16x32_bf16(af[g][1], b1, acc[g][j], 0, 0, 0);
    }
  }
  // store: D row = q*4+r, col = cl
  u16* outb = qkv + ((size_t)(b * 192) << 16) + p0;
  for (int g = 0; g < 3; ++g) {
    int rowb = w * 48 + g * 16 + q * 4;
#pragma unroll
    for (int r = 0; r < 4; ++r) {
      u16* orow = outb + ((size_t)(rowb + r) << 16);
#pragma unroll
      for (int j = 0; j < 8; ++j) orow[j * 16 + cl] = f2bf(acc[g][j][r]);
    }
  }
}

// ---------------- 1/||plane|| for q,k channels (from bf16 qkv) ----------------
__global__ void k_rnorm(const u16* __restrict__ qkv, float* __restrict__ rnorm) {
  int b = blockIdx.x >> 7, ch = blockIdx.x & 127;
  const uint2* p2 = (const uint2*)(qkv + ((size_t)(b * 192 + ch) << 16));
  int t = threadIdx.x;
  float s = 0.f;
  for (int i = 0; i < 64; ++i) {
    uint2 v = p2[t + 256 * i];
    float a = bf2f(v.x & 0xffff), bq = bf2f(v.x >> 16);
    float c = bf2f(v.y & 0xffff), d = bf2f(v.y >> 16);
    s += a * a + bq * bq + c * c + d * d;
  }
  for (int off = 32; off; off >>= 1) s += __shfl_down(s, off);
  __shared__ float lds[4];
  if ((t & 63) == 0) lds[t >> 6] = s;
  __syncthreads();
  if (t == 0) {
    float tot = lds[0] + lds[1] + lds[2] + lds[3];
    rnorm[blockIdx.x] = 1.f / fmaxf(sqrtf(tot), 1e-12f);
  }
}

// ---------------- depthwise 3x3+5x5 conv, writes cw*conv to d_out (fp32) ----------------
__global__ void k_conv(const float* __restrict__ x, const float* __restrict__ w3,
                       const float* __restrict__ b3, const float* __restrict__ w5,
                       const float* __restrict__ b5, const float* __restrict__ cwaw,
                       float* __restrict__ outmix) {
  int rt = blockIdx.x & 31, bc = blockIdx.x >> 5, c = bc & 63, b = bc >> 6;
  int r0 = rt * 8;
  const float* xp = x + ((size_t)bc << 16);
  __shared__ float xs[12][256];
  int y = threadIdx.x;
  for (int rr = 0; rr < 12; ++rr) {
    int gr = r0 - 2 + rr;
    xs[rr][y] = (gr >= 0 && gr < 256) ? xp[(size_t)gr * 256 + y] : 0.f;
  }
  __syncthreads();
  float W3[9], W5[25];
#pragma unroll
  for (int i = 0; i < 9; ++i) W3[i] = w3[c * 9 + i];
#pragma unroll
  for (int i = 0; i < 25; ++i) W5[i] = w5[c * 25 + i];
  float bias = b3[c] + b5[c];
  float cw = cwaw[b * 2];
  float* op = outmix + ((size_t)bc << 16);
  for (int k = 0; k < 8; ++k) {
    float a = bias;
#pragma unroll
    for (int di = 0; di < 3; ++di)
#pragma unroll
      for (int dj = 0; dj < 3; ++dj) {
        int yy = y + dj - 1;
        float xv = (yy >= 0 && yy < 256) ? xs[k + 1 + di][yy] : 0.f;
        a += W3[di * 3 + dj] * xv;
      }
#pragma unroll
    for (int di = 0; di < 5; ++di)
#pragma unroll
      for (int dj = 0; dj < 5; ++dj) {
        int yy = y + dj - 2;
        float xv = (yy >= 0 && yy < 256) ? xs[k + di][yy] : 0.f;
        a += W5[di * 5 + dj] * xv;
      }
    op[(size_t)(r0 + k) * 256 + y] = cw * a;
  }
}

// ---------------- axial attention, MFMA bf16, operands direct from global ----------------
__global__ __launch_bounds__(256) void k_attn(
    const u16* __restrict__ qkv, const float* __restrict__ rnorm,
    const float* __restrict__ scale, u16* __restrict__ oh, u16* __restrict__ ov) {
  __shared__ __align__(16) unsigned char smem[34816];
  u16* Pls = (u16*)smem;                // [64][264] bf16
  float* red = (float*)(smem + 33792);  // [4][64]
  float* Osf = (float*)smem;            // [32][260] (dir1 store; Pls dead, barrier-protected)

  int t = threadIdx.x;
  int w = t >> 6, l = t & 63, q = l >> 4, cl = l & 15;
  int idx = blockIdx.x;
  int rt = idx & 3, dir = (idx >> 2) & 1, c = (idx >> 3) & 63, b = idx >> 9;
  int r0 = rt << 6;

  const size_t P = 65536;
  const u16* Qp = qkv + (size_t)(b * 192 + c) * P;
  const u16* Kp = qkv + (size_t)(b * 192 + 64 + c) * P;
  const u16* Vp = qkv + (size_t)(b * 192 + 128 + c) * P;

  float sc = rnorm[b * 128 + c] * rnorm[b * 128 + 64 + c] * scale[c >> 3];

  f32x4 Sa[4][4];
  f32x4 zero = {0.f, 0.f, 0.f, 0.f};
#pragma unroll
  for (int i = 0; i < 4; ++i)
#pragma unroll
    for (int j = 0; j < 4; ++j) Sa[i][j] = zero;

  // ---- S phase: 8 k-windows of 32 ----
  for (int yw = 0; yw < 8; ++yw) {
    int y0 = yw << 5;
    bf16x8 af[4], bfr[4];
    if (dir == 0) {
#pragma unroll
      for (int i = 0; i < 4; ++i)
        af[i] = *(const bf16x8*)&Qp[(size_t)(r0 + i * 16 + cl) * 256 + y0 + q * 8];
#pragma unroll
      for (int j = 0; j < 4; ++j)
        bfr[j] = *(const bf16x8*)&Kp[(size_t)(w * 64 + j * 16 + cl) * 256 + y0 + q * 8];
    } else {
#pragma unroll
      for (int i = 0; i < 4; ++i) {
        bf16x8 tmp;
#pragma unroll
        for (int jj = 0; jj < 8; ++jj)
          tmp[jj] = (short)Qp[(y0 + q * 8 + jj) * 256 + r0 + i * 16 + cl];
        af[i] = tmp;
      }
#pragma unroll
      for (int j = 0; j < 4; ++j) {
        bf16x8 tmp;
#pragma unroll
        for (int jj = 0; jj < 8; ++jj)
          tmp[jj] = (short)Kp[(y0 + q * 8 + jj) * 256 + w * 64 + j * 16 + cl];
        bfr[j] = tmp;
      }
    }
#pragma unroll
    for (int i = 0; i < 4; ++i)
#pragma unroll
      for (int j = 0; j < 4; ++j)
        Sa[i][j] = __builtin_amdgcn_mfma_f32_16x16x32_bf16(af[i], bfr[j], Sa[i][j], 0, 0, 0);
  }

  // ---- softmax over cols (rows = i*16+q*4+r, cols = w*64+j*16+cl) ----
#pragma unroll
  for (int i = 0; i < 4; ++i)
#pragma unroll
    for (int j = 0; j < 4; ++j) Sa[i][j] *= sc;

  float mx[4][4], sm[4][4];
#pragma unroll
  for (int i = 0; i < 4; ++i)
#pragma unroll
    for (int r = 0; r < 4; ++r) {
      float m = fmaxf(fmaxf(Sa[i][0][r], Sa[i][1][r]), fmaxf(Sa[i][2][r], Sa[i][3][r]));
#pragma unroll
      for (int off = 1; off < 16; off <<= 1) m = fmaxf(m, __shfl_xor(m, off));
      mx[i][r] = m;
    }
  if (cl == 0) {
#pragma unroll
    for (int i = 0; i < 4; ++i)
#pragma unroll
      for (int r = 0; r < 4; ++r) red[w * 64 + i * 16 + q * 4 + r] = mx[i][r];
  }
  __syncthreads();
#pragma unroll
  for (int i = 0; i < 4; ++i)
#pragma unroll
    for (int r = 0; r < 4; ++r) {
      int rho = i * 16 + q * 4 + r;
      mx[i][r] = fmaxf(fmaxf(red[rho], red[64 + rho]), fmaxf(red[128 + rho], red[192 + rho]));
    }
  __syncthreads();
#pragma unroll
  for (int i = 0; i < 4; ++i)
#pragma unroll
    for (int r = 0; r < 4; ++r) {
      float s0 = 0.f;
#pragma unroll
      for (int j = 0; j < 4; ++j) {
        float e = __expf(Sa[i][j][r] - mx[i][r]);
        Sa[i][j][r] = e;
        s0 += e;
      }
#pragma unroll
      for (int off = 1; off < 16; off <<= 1) s0 += __shfl_xor(s0, off);
      sm[i][r] = s0;
    }
  if (cl == 0) {
#pragma unroll
    for (int i = 0; i < 4; ++i)
#pragma unroll
      for (int r = 0; r < 4; ++r) red[w * 64 + i * 16 + q * 4 + r] = sm[i][r];
  }
  __syncthreads();
#pragma unroll
  for (int i = 0; i < 4; ++i)
#pragma unroll
    for (int r = 0; r < 4; ++r) {
      int rho = i * 16 + q * 4 + r;
      sm[i][r] = 1.f / (red[rho] + red[64 + rho] + red[128 + rho] + red[192 + rho]);
    }
  // P -> LDS row-major [row][z]
#pragma unroll
  for (int i = 0; i < 4; ++i)
#pragma unroll
    for (int r = 0; r < 4; ++r) {
      int rho = i * 16 + q * 4 + r;
#pragma unroll
      for (int j = 0; j < 4; ++j)
        Pls[rho * 264 + w * 64 + j * 16 + cl] = f2bf(Sa[i][j][r] * sm[i][r]);
    }
  __syncthreads();

  // ---- O = P V over 8 z-windows ----
  f32x4 Oa[4][4];
#pragma unroll
  for (int i = 0; i < 4; ++i)
#pragma unroll
    for (int j = 0; j < 4; ++j) Oa[i][j] = zero;
  for (int zw = 0; zw < 8; ++zw) {
    int z0 = zw << 5;
    bf16x8 af[4], bfr[4];
#pragma unroll
    for (int i = 0; i < 4; ++i) af[i] = *(const bf16x8*)&Pls[(i * 16 + cl) * 264 + z0 + q * 8];
    if (dir == 0) {
#pragma unroll
      for (int j = 0; j < 4; ++j) {
        bf16x8 tmp;
#pragma unroll
        for (int jj = 0; jj < 8; ++jj)
          tmp[jj] = (short)Vp[(z0 + q * 8 + jj) * 256 + w * 64 + j * 16 + cl];
        bfr[j] = tmp;
      }
    } else {
#pragma unroll
      for (int j = 0; j < 4; ++j)
        bfr[j] = *(const bf16x8*)&Vp[(size_t)(w * 64 + j * 16 + cl) * 256 + z0 + q * 8];
    }
#pragma unroll
    for (int i = 0; i < 4; ++i)
#pragma unroll
      for (int j = 0; j < 4; ++j)
        Oa[i][j] = __builtin_amdgcn_mfma_f32_16x16x32_bf16(af[i], bfr[j], Oa[i][j], 0, 0, 0);
  }

  // ---- store ----
  if (dir == 0) {
    u16* op = oh + (size_t)(b * 64 + c) * P;
#pragma unroll
    for (int i = 0; i < 4; ++i)
#pragma unroll
      for (int j = 0; j < 4; ++j)
#pragma unroll
        for (int r = 0; r < 4; ++r)
          op[(size_t)(r0 + i * 16 + q * 4 + r) * 256 + w * 64 + j * 16 + cl] = f2bf(Oa[i][j][r]);
  } else {
    u16* op = ov + (size_t)(b * 64 + c) * P;
    __syncthreads();  // Pls (aliasing Osf) may still be read by lagging waves
    for (int h = 0; h < 2; ++h) {
#pragma unroll
      for (int ii = 0; ii < 2; ++ii) {
        int i = h * 2 + ii;
#pragma unroll
        for (int j = 0; j < 4; ++j)
#pragma unroll
          for (int r = 0; r < 4; ++r)
            Osf[(ii * 16 + q * 4 + r) * 260 + w * 64 + j * 16 + cl] = Oa[i][j][r];
      }
      __syncthreads();
      int rr = t & 31, xb = t >> 5;
      for (int xx = 0; xx < 32; ++xx) {
        int xcol = xx * 8 + xb;
        op[(size_t)xcol * 256 + r0 + h * 32 + rr] = f2bf(Osf[rr * 260 + xcol]);
      }
      __syncthreads();
    }
  }
}

// ---------------- mix + 64x64 projection as MFMA GEMM, in place on d_out ----------------
// block: 64 out-rows x 256 px. wave w: rows w*16..w*16+15.
__global__ __launch_bounds__(256) void k_final(
    float* __restrict__ dout, const u16* __restrict__ oh, const u16* __restrict__ ov,
    const float* __restrict__ wp, const float* __restrict__ bp,
    const float* __restrict__ cwaw) {
  __shared__ u16 Ms[256 * 72];  // B^T: [px][ch]
  __shared__ u16 Ws[64 * 72];   // A: [row][ch]
  int t = threadIdx.x;
  int b = blockIdx.x >> 8;
  int p0 = (blockIdx.x & 255) << 8;
  float aw = cwaw[b * 2 + 1];

  // stage wp (64x64 fp32 -> bf16)
  {
    int row = t >> 2, c0 = (t & 3) << 4;
    const float* src = wp + row * 64 + c0;
    unsigned pk[8];
#pragma unroll
    for (int j = 0; j < 8; ++j)
      pk[j] = (unsigned)f2bf(src[2 * j]) | ((unsigned)f2bf(src[2 * j + 1]) << 16);
    uint4* dst = (uint4*)&Ws[row * 72 + c0];
    dst[0] = make_uint4(pk[0], pk[1], pk[2], pk[3]);
    dst[1] = make_uint4(pk[4], pk[5], pk[6], pk[7]);
  }
  // stage mixed m = conv_mix + aw*(oh+ov): 64ch x 256px -> Ms[px][ch]
  {
    size_t base = ((size_t)(b * 64) << 16) + p0 + t;
    for (int c = 0; c < 64; ++c) {
      size_t off = base + ((size_t)c << 16);
      float m = dout[off] + aw * (bf2f(oh[off]) + bf2f(ov[off]));
      Ms[t * 72 + c] = f2bf(m);
    }
  }
  __syncthreads();

  int w = t >> 6, l = t & 63, q = l >> 4, cl = l & 15;
  bf16x8 af0 = *(const bf16x8*)&Ws[(w * 16 + cl) * 72 + q * 8];
  bf16x8 af1 = *(const bf16x8*)&Ws[(w * 16 + cl) * 72 + 32 + q * 8];

  f32x4 acc[16];
  f32x4 zero = {0.f, 0.f, 0.f, 0.f};
#pragma unroll
  for (int j = 0; j < 16; ++j) acc[j] = zero;

  for (int j = 0; j < 16; ++j) {
    bf16x8 b0 = *(const bf16x8*)&Ms[(j * 16 + cl) * 72 + q * 8];
    bf16x8 b1 = *(const bf16x8*)&Ms[(j * 16 + cl) * 72 + 32 + q * 8];
    acc[j] = __builtin_amdgcn_mfma_f32_16x16x32_bf16(af0, b0, acc[j], 0, 0, 0);
    acc[j] = __builtin_amdgcn_mfma_f32_16x16x32_bf16(af1, b1, acc[j], 0, 0, 0);
  }

  float bpv[4];
#pragma unroll
  for (int r = 0; r < 4; ++r) bpv[r] = bp[w * 16 + q * 4 + r];
  float* outb = dout + ((size_t)(b * 64) << 16) + p0;
#pragma unroll
  for (int r = 0; r < 4; ++r) {
    float* orow = outb + ((size_t)(w * 16 + q * 4 + r) << 16);
#pragma unroll
    for (int j = 0; j < 16; ++j) orow[j * 16 + cl] = acc[j][r] + bpv[r];
  }
}

extern "C" void kernel_launch(void* const* d_in, const int* in_sizes, int n_in,
                              void* d_out, int out_size, void* d_ws, size_t ws_size,
                              hipStream_t stream) {
  const float* x = (const float*)d_in[0];
  const float* w3 = (const float*)d_in[1];
  const float* b3 = (const float*)d_in[2];
  const float* w5 = (const float*)d_in[3];
  const float* b5 = (const float*)d_in[4];
  const float* wqkv = (const float*)d_in[5];
  const float* scale = (const float*)d_in[6];
  const float* g1w = (const float*)d_in[7];
  const float* g1b = (const float*)d_in[8];
  const float* g2w = (const float*)d_in[9];
  const float* g2b = (const float*)d_in[10];
  const float* wp = (const float*)d_in[11];
  const float* bp = (const float*)d_in[12];
  float* out = (float*)d_out;

  char* ws = (char*)d_ws;
  u16* qkv = (u16*)(ws);
  u16* ohb = (u16*)(ws + 100663296ull);
  u16* ovb = (u16*)(ws + 134217728ull);
  float* fs = (float*)(ws + 167772160ull);
  float* gxsum = fs;        // 256
  float* cwaw = fs + 256;   // 8
  float* rnorm = fs + 264;  // 512

  k_gx<<<256, 256, 0, stream>>>(x, gxsum);
  k_gate<<<1, 64, 0, stream>>>(gxsum, g1w, g1b, g2w, g2b, cwaw);
  k_qkv<<<2048, 256, 0, stream>>>(x, wqkv, qkv);
  k_rnorm<<<512, 256, 0, stream>>>(qkv, rnorm);
  k_conv<<<8192, 256, 0, stream>>>(x, w3, b3, w5, b5, cwaw, out);
  k_attn<<<2048, 256, 0, stream>>>(qkv, rnorm, scale, ohb, ovb);
  k_final<<<1024, 256, 0, stream>>>(out, ohb, ovb, wp, bp, cwaw);
}